// Round 9
// baseline (248.152 us; speedup 1.0000x reference)
//
#include <hip/hip_runtime.h>
#include <stdint.h>

// ---------------------------------------------------------------------------
// Fused RBF histogram:  hist[o,i] = sum_n exp(-||x_n - c_o||^2 / 2) * x[n,i]
// N=524288, IN=64, OUT=128.  fp32 in/out.
//
// R9: BARRIER-FREE main loop. R1-R8 evidence: ~40us of the ~62us kernel is
// stall that survived occupancy/LDS/prefetch changes — the common factor was
// the phase-locked __syncthreads loop (whole-CU convoy). This round:
//  - x loaded DIRECTLY from global in MFMA A-frag layout (lane=row l15,
//    cols quad*8; 4x float4) — no shared staging, no "tile ready" barrier.
//    The 4 waves/block read the same 4KB tile; L1 serves waves 2-4.
//  - x2 via 2x shfl_xor (quad reduce) + 4x shfl (row redistribute).
//  - transpose via WAVE-PRIVATE LDS patch (write A-layout, read b64
//    transposed, same-wave => lgkmcnt ordering only, no barrier).
//  - P in registers (R8 identity), stage B MFMA16, exp2 +38 bias (R8).
//  - ZERO __syncthreads in the loop; 12 waves/CU free-running.
//  - reduce kernel plain-stores (zero_out only needed in atomic fallback).
// ---------------------------------------------------------------------------

typedef _Float16 half8v __attribute__((ext_vector_type(8)));
typedef _Float16 half4v __attribute__((ext_vector_type(4)));
typedef __fp16  fp16x2 __attribute__((ext_vector_type(2)));
typedef float floatx4 __attribute__((ext_vector_type(4)));

#define GRIDN 1024       // blocks; 32768 16-row tiles / 1024 = 32 tiles/block
#define NITER 32
#define LOG2E 1.4426950408889634f
#define PBIAS 38.0f                       // P scaled by 2^38 into fp16 range
#define PUNSCALE 3.637978807091713e-12f   // 2^-38 (exact power of two)

#if __has_builtin(__builtin_amdgcn_exp2f)
#define EXP2F(x) __builtin_amdgcn_exp2f(x)
#else
#define EXP2F(x) exp2f(x)
#endif

// pack two fp32 -> fp16x2, RTZ — only for exactly-representable values
static __device__ __forceinline__ unsigned int pk16z(float a, float b) {
  fp16x2 h = __builtin_amdgcn_cvt_pkrtz(a, b);
  return __builtin_bit_cast(unsigned int, h);
}
// pack two fp32 -> fp16x2, RNE
static __device__ __forceinline__ unsigned int pk16(float a, float b) {
  unsigned short ha = __builtin_bit_cast(unsigned short, (_Float16)a);
  unsigned short hb = __builtin_bit_cast(unsigned short, (_Float16)b);
  return (unsigned int)ha | ((unsigned int)hb << 16);
}
static __device__ __forceinline__ half4v mkh4(unsigned int lo, unsigned int hi) {
  uint2 u{lo, hi};
  return __builtin_bit_cast(half4v, u);
}
static __device__ __forceinline__ half8v mkh8(unsigned int a, unsigned int b,
                                              unsigned int c, unsigned int d) {
  uint4 u{a, b, c, d};
  return __builtin_bit_cast(half8v, u);
}

static __device__ __forceinline__ floatx4 mfma32(half8v a, half8v b, floatx4 c) {
  return __builtin_amdgcn_mfma_f32_16x16x32_f16(a, b, c, 0, 0, 0);
}
static __device__ __forceinline__ floatx4 mfma16(half4v a, half4v b, floatx4 c) {
  return __builtin_amdgcn_mfma_f32_16x16x16f16(a, b, c, 0, 0, 0);
}

// transpose patch row stride 72 shorts = 144 B: 16B-aligned, bank step 4
// -> <=2-way conflicts (free).
#define LSTR 72

__global__ __launch_bounds__(256, 3) void rbf_hist_kernel(
    const float* __restrict__ x, const float* __restrict__ c,
    float* __restrict__ out, float* __restrict__ ws, int use_ws) {
  __shared__ unsigned short sT[4][16][LSTR];  // per-WAVE transpose patch

  const int t    = threadIdx.x;    // 0..255
  const int lane = t & 63;
  const int w    = t >> 6;         // wave 0..3; owns o-tiles {2w, 2w+1}
  const int l15  = lane & 15;
  const int quad = lane >> 4;

  // ---- one-time: c*log2e fp16 hi/lo fragments for this wave's 2 o-tiles ----
  half8v chi[2][2], clo[2][2];
  float m2c[2];                    // -0.5*log2e*||c_o||^2 + PBIAS
#pragma unroll
  for (int oo = 0; oo < 2; ++oo) {
    const int ot = 2 * w + oo;
    float sq = 0.f;
#pragma unroll
    for (int s = 0; s < 2; ++s) {
      const float* p = c + (ot * 16 + l15) * 64 + s * 32 + quad * 8;
      float4 va = *(const float4*)(p);
      float4 vb = *(const float4*)(p + 4);
      float f[8] = {va.x, va.y, va.z, va.w, vb.x, vb.y, vb.z, vb.w};
      unsigned int h[4], l[4];
#pragma unroll
      for (int jp = 0; jp < 4; ++jp) {
        float a = f[2 * jp], b = f[2 * jp + 1];
        sq = fmaf(a, a, sq);
        sq = fmaf(b, b, sq);
        a *= LOG2E; b *= LOG2E;
        unsigned int hp = pk16(a, b);      // RNE
        float ha = (float)__builtin_bit_cast(_Float16, (unsigned short)(hp & 0xffffu));
        float hb = (float)__builtin_bit_cast(_Float16, (unsigned short)(hp >> 16));
        h[jp] = hp;
        l[jp] = pk16z(a - ha, b - hb);     // c_lo correction
      }
      chi[oo][s] = mkh8(h[0], h[1], h[2], h[3]);
      clo[oo][s] = mkh8(l[0], l[1], l[2], l[3]);
    }
    sq += __shfl_xor(sq, 16);
    sq += __shfl_xor(sq, 32);
    m2c[oo] = fmaf(-0.5f * LOG2E, sq, PBIAS);
  }

  // identity B-frag for the transpose MFMA: I[k=quad*4+j][col=l15]
  half4v iden;
  {
    float e0 = (quad * 4 + 0 == l15) ? 1.f : 0.f;
    float e1 = (quad * 4 + 1 == l15) ? 1.f : 0.f;
    float e2 = (quad * 4 + 2 == l15) ? 1.f : 0.f;
    float e3 = (quad * 4 + 3 == l15) ? 1.f : 0.f;
    iden = mkh4(pk16z(e0, e1), pk16z(e2, e3));  // exact
  }

  // persistent histogram accumulators: 2 o-tiles x 4 i-tiles (scaled 2^38)
  floatx4 hacc[2][4];
#pragma unroll
  for (int a = 0; a < 2; ++a)
#pragma unroll
    for (int b = 0; b < 4; ++b) {
      floatx4 z = {0.f, 0.f, 0.f, 0.f};
      hacc[a][b] = z;
    }

  // ---- first tile load, directly in A-frag layout ----
  // lane (l15,quad) reads x[tile*16+l15][s*32+quad*8 .. +7] (2x float4 per s)
  float4 v[4];
  {
    const float* rp = x + ((size_t)blockIdx.x * 16 + l15) * 64;
    v[0] = *(const float4*)(rp + quad * 8);
    v[1] = *(const float4*)(rp + quad * 8 + 4);
    v[2] = *(const float4*)(rp + 32 + quad * 8);
    v[3] = *(const float4*)(rp + 32 + quad * 8 + 4);
  }

  for (int it = 0; it < NITER; ++it) {
    // ---- convert current tile (regs) + exact fp32 x2 ----
    float sq = 0.f;
#pragma unroll
    for (int u = 0; u < 4; ++u) {
      sq = fmaf(v[u].x, v[u].x, sq);
      sq = fmaf(v[u].y, v[u].y, sq);
      sq = fmaf(v[u].z, v[u].z, sq);
      sq = fmaf(v[u].w, v[u].w, sq);
    }
    half8v xh0 = mkh8(pk16(v[0].x, v[0].y), pk16(v[0].z, v[0].w),
                      pk16(v[1].x, v[1].y), pk16(v[1].z, v[1].w));
    half8v xh1 = mkh8(pk16(v[2].x, v[2].y), pk16(v[2].z, v[2].w),
                      pk16(v[3].x, v[3].y), pk16(v[3].z, v[3].w));

    // wave-private transpose patch (same-wave produce/consume, no barrier)
    *(uint4*)&sT[w][l15][quad * 8]      = __builtin_bit_cast(uint4, xh0);
    *(uint4*)&sT[w][l15][32 + quad * 8] = __builtin_bit_cast(uint4, xh1);

    // ---- prefetch next tile (no barrier will ever drain it early) ----
    if (it < NITER - 1) {
      const float* np =
          x + ((size_t)(blockIdx.x + (it + 1) * GRIDN) * 16 + l15) * 64;
      v[0] = *(const float4*)(np + quad * 8);
      v[1] = *(const float4*)(np + quad * 8 + 4);
      v[2] = *(const float4*)(np + 32 + quad * 8);
      v[3] = *(const float4*)(np + 32 + quad * 8 + 4);
    }

    // x2: reduce over quads (row l15), then redistribute to C-row lanes
    sq += __shfl_xor(sq, 16);
    sq += __shfl_xor(sq, 32);
    float m2x[4];
#pragma unroll
    for (int e = 0; e < 4; ++e)
      m2x[e] = -0.5f * LOG2E * __shfl(sq, quad * 4 + e);

    // ---- stage A: scores -> exp2 -> P fp16 A-frags (registers) ----
    half4v P[2];
#pragma unroll
    for (int oo = 0; oo < 2; ++oo) {
      floatx4 accA = {m2x[0] + m2c[oo], m2x[1] + m2c[oo],
                      m2x[2] + m2c[oo], m2x[3] + m2c[oo]};
      floatx4 accB = {0.f, 0.f, 0.f, 0.f};
      accA = mfma32(xh0, chi[oo][0], accA);
      accB = mfma32(xh1, clo[oo][1], accB);
      accA = mfma32(xh1, chi[oo][1], accA);
      accB = mfma32(xh0, clo[oo][0], accB);
      floatx4 acc = accA + accB;  // == log2e*(-d/2) + 38
      P[oo] = mkh4(pk16(EXP2F(acc[0]), EXP2F(acc[1])),
                   pk16(EXP2F(acc[2]), EXP2F(acc[3])));
    }

    // ---- transpose x via wave-private LDS + MFMA identity ----
    half4v XT[4];
#pragma unroll
    for (int itl = 0; itl < 4; ++itl) {
      half4v ax = *(const half4v*)&sT[w][l15][itl * 16 + quad * 4];
      floatx4 z = {0.f, 0.f, 0.f, 0.f};
      floatx4 d = mfma16(ax, iden, z);
      XT[itl] = mkh4(pk16z(d[0], d[1]), pk16z(d[2], d[3]));  // exact
    }

    // ---- stage B: hist += P * X^T (K=16), registers only ----
#pragma unroll
    for (int oo = 0; oo < 2; ++oo)
#pragma unroll
      for (int itl = 0; itl < 4; ++itl)
        hacc[oo][itl] = mfma16(P[oo], XT[itl], hacc[oo][itl]);
  }

  // ---- epilogue (unscale by 2^-38, exact) ----
  // D: i = itl*16 + l15, o = (2w+oo)*16 + quad*4 + e
  if (use_ws) {
    float* part = ws + (size_t)blockIdx.x * 8192;
#pragma unroll
    for (int oo = 0; oo < 2; ++oo)
#pragma unroll
      for (int itl = 0; itl < 4; ++itl)
#pragma unroll
        for (int e = 0; e < 4; ++e) {
          int o = (2 * w + oo) * 16 + quad * 4 + e;
          int i = itl * 16 + l15;
          part[o * 64 + i] = hacc[oo][itl][e] * PUNSCALE;
        }
  } else {
#pragma unroll
    for (int oo = 0; oo < 2; ++oo)
#pragma unroll
      for (int itl = 0; itl < 4; ++itl)
#pragma unroll
        for (int e = 0; e < 4; ++e) {
          int o = (2 * w + oo) * 16 + quad * 4 + e;
          int i = itl * 16 + l15;
          atomicAdd(out + o * 64 + i, hacc[oo][itl][e] * PUNSCALE);
        }
  }
}

// out[e] = sum over 1024 per-block partials (plain store; no zero needed)
__global__ void reduce_store_kernel(const float* __restrict__ ws,
                                    float* __restrict__ out) {
  const int e = blockIdx.x * 256 + threadIdx.x;  // 8192 threads
  float s = 0.f;
#pragma unroll 8
  for (int b = 0; b < GRIDN; ++b) s += ws[(size_t)b * 8192 + e];
  out[e] = s;
}

__global__ void zero_out_kernel(float* out, int n) {
  int i = blockIdx.x * 256 + threadIdx.x;
  if (i < n) out[i] = 0.f;
}

extern "C" void kernel_launch(void* const* d_in, const int* in_sizes, int n_in,
                              void* d_out, int out_size, void* d_ws, size_t ws_size,
                              hipStream_t stream) {
  (void)in_sizes; (void)n_in;
  const float* x = (const float*)d_in[0];        // [524288, 64]
  const float* c = (const float*)d_in[1];        // [128, 64]
  float* out = (float*)d_out;                    // [128, 64]
  float* ws  = (float*)d_ws;

  const int use_ws = (ws_size >= (size_t)GRIDN * 8192 * sizeof(float)) ? 1 : 0;

  if (use_ws) {
    rbf_hist_kernel<<<GRIDN, 256, 0, stream>>>(x, c, out, ws, 1);
    reduce_store_kernel<<<32, 256, 0, stream>>>(ws, out);
  } else {
    zero_out_kernel<<<(out_size + 255) / 256, 256, 0, stream>>>(out, out_size);
    rbf_hist_kernel<<<GRIDN, 256, 0, stream>>>(x, c, out, ws, 0);
  }
}

// Round 10
// 217.184 us; speedup vs baseline: 1.1426x; 1.1426x over previous
//
#include <hip/hip_runtime.h>
#include <stdint.h>

// ---------------------------------------------------------------------------
// Fused RBF histogram:  hist[o,i] = sum_n exp(-||x_n - c_o||^2 / 2) * x[n,i]
// N=524288, IN=64, OUT=128.  fp32 in/out.
//
// R10: R8's structure (fastest so far, ~60us) at FULL OCCUPANCY.
// R9 profile: Occupancy 38%, all pipes <40% -> latency-bound; barriers
// exonerated (barrier-free R9 was *slower* via redundant loads).
//  - 256-thr blocks, wave owns 2 o-tiles (chi 16 VGPR), c_lo DROPPED
//    (error margin 7.6x; c-side fp16 err ~= x-side -> ~2.9e-11, 3.8x margin)
//    -> ~100 VGPR, launch_bounds(256,4) caps 128 -> 8 blocks/CU.
//  - grid 2048 = 8 blocks/CU = 32 waves/CU (was 8 waves/CU in R8).
//  - stage A = 2 MFMA32/oo; P in regs (R8 identity); transpose-MFMA (R8);
//    exp2 +38 bias (R8); LDS 4.75 KB (sXh strip + sX2), 2 barriers/iter.
//  - reduce fixed: 65536 threads, 8 coalesced partial-sums/elem + atomic
//    (R9's 32-block version was ~33us; this ~8us).
// ---------------------------------------------------------------------------

typedef _Float16 half8v __attribute__((ext_vector_type(8)));
typedef _Float16 half4v __attribute__((ext_vector_type(4)));
typedef __fp16  fp16x2 __attribute__((ext_vector_type(2)));
typedef float floatx4 __attribute__((ext_vector_type(4)));

#define GRIDN 2048       // 8 blocks/CU x 256 CUs
#define NITER 8          // 16384 32-row strips / 2048 blocks
#define LOG2E 1.4426950408889634f
#define PBIAS 38.0f                       // P scaled by 2^38 into fp16 range
#define PUNSCALE 3.637978807091713e-12f   // 2^-38 (exact power of two)

#if __has_builtin(__builtin_amdgcn_exp2f)
#define EXP2F(x) __builtin_amdgcn_exp2f(x)
#else
#define EXP2F(x) exp2f(x)
#endif

// pack two fp32 -> fp16x2, RTZ — only for exactly-representable values
static __device__ __forceinline__ unsigned int pk16z(float a, float b) {
  fp16x2 h = __builtin_amdgcn_cvt_pkrtz(a, b);
  return __builtin_bit_cast(unsigned int, h);
}
// pack two fp32 -> fp16x2, RNE
static __device__ __forceinline__ unsigned int pk16(float a, float b) {
  unsigned short ha = __builtin_bit_cast(unsigned short, (_Float16)a);
  unsigned short hb = __builtin_bit_cast(unsigned short, (_Float16)b);
  return (unsigned int)ha | ((unsigned int)hb << 16);
}
static __device__ __forceinline__ half4v mkh4(unsigned int lo, unsigned int hi) {
  uint2 u{lo, hi};
  return __builtin_bit_cast(half4v, u);
}
static __device__ __forceinline__ half8v mkh8(unsigned int a, unsigned int b,
                                              unsigned int c, unsigned int d) {
  uint4 u{a, b, c, d};
  return __builtin_bit_cast(half8v, u);
}

static __device__ __forceinline__ floatx4 mfma32(half8v a, half8v b, floatx4 c) {
  return __builtin_amdgcn_mfma_f32_16x16x32_f16(a, b, c, 0, 0, 0);
}
static __device__ __forceinline__ floatx4 mfma16(half4v a, half4v b, floatx4 c) {
  return __builtin_amdgcn_mfma_f32_16x16x16f16(a, b, c, 0, 0, 0);
}

// sXh row stride 72 shorts = 144 B: 16B-aligned rows, bank step 4 words
// -> <=2-way conflicts on b128/b64 frag reads (free per m136).
#define LSTR 72

__global__ __launch_bounds__(256, 4) void rbf_hist_kernel(
    const float* __restrict__ x, const float* __restrict__ c,
    float* __restrict__ out, float* __restrict__ ws, int use_ws) {
  __shared__ unsigned short sXh[32][LSTR];  // fp16(x) strip, row-major [n][i]
  __shared__ float          sX2[32];        // -0.5*log2e*||x_n||^2 (fp32 exact)

  const int t    = threadIdx.x;    // 0..255
  const int lane = t & 63;
  const int w    = t >> 6;         // wave 0..3; owns o-tiles {2w, 2w+1}
  const int l15  = lane & 15;
  const int quad = lane >> 4;

  // ---- one-time: c*log2e fp16 (RNE) fragments for this wave's 2 o-tiles ----
  // stage-A B-frag: B[k=i][col=o]: lane reads c[ot*16+l15][s*32+quad*8 ..+7]
  half8v chi[2][2];
  float m2c[2];                    // -0.5*log2e*||c_o||^2 + PBIAS
#pragma unroll
  for (int oo = 0; oo < 2; ++oo) {
    const int ot = 2 * w + oo;
    float sq = 0.f;
#pragma unroll
    for (int s = 0; s < 2; ++s) {
      const float* p = c + (ot * 16 + l15) * 64 + s * 32 + quad * 8;
      float4 va = *(const float4*)(p);
      float4 vb = *(const float4*)(p + 4);
      float f[8] = {va.x, va.y, va.z, va.w, vb.x, vb.y, vb.z, vb.w};
      unsigned int h[4];
#pragma unroll
      for (int jp = 0; jp < 4; ++jp) {
        float a = f[2 * jp], b = f[2 * jp + 1];
        sq = fmaf(a, a, sq);
        sq = fmaf(b, b, sq);
        h[jp] = pk16(a * LOG2E, b * LOG2E);   // RNE
      }
      chi[oo][s] = mkh8(h[0], h[1], h[2], h[3]);
    }
    sq += __shfl_xor(sq, 16);
    sq += __shfl_xor(sq, 32);
    m2c[oo] = fmaf(-0.5f * LOG2E, sq, PBIAS);
  }

  // identity B-frag for the transpose MFMA: I[k=quad*4+j][col=l15]
  half4v iden;
  {
    float e0 = (quad * 4 + 0 == l15) ? 1.f : 0.f;
    float e1 = (quad * 4 + 1 == l15) ? 1.f : 0.f;
    float e2 = (quad * 4 + 2 == l15) ? 1.f : 0.f;
    float e3 = (quad * 4 + 3 == l15) ? 1.f : 0.f;
    iden = mkh4(pk16z(e0, e1), pk16z(e2, e3));  // exact
  }

  // persistent histogram accumulators: 2 o-tiles x 4 i-tiles (scaled 2^38)
  floatx4 hacc[2][4];
#pragma unroll
  for (int a = 0; a < 2; ++a)
#pragma unroll
    for (int b = 0; b < 4; ++b) {
      floatx4 z = {0.f, 0.f, 0.f, 0.f};
      hacc[a][b] = z;
    }

  // staging map: thread t -> row r=t>>3 (0..31), cols q*8 .. q*8+7 (q=t&7)
  const int r = t >> 3, q = t & 7;
  float4 v[2];
  {
    const float* p = x + ((size_t)blockIdx.x * 32 + r) * 64 + q * 8;
    v[0] = *(const float4*)(p);
    v[1] = *(const float4*)(p + 4);
  }

  for (int it = 0; it < NITER; ++it) {
    __syncthreads();  // prev strip's sXh reads done -> safe to overwrite

    // ---- staging: fp16 RNE convert -> LDS row-major + exact fp32 x2 ----
    {
      float f0 = v[0].x, f1 = v[0].y, f2 = v[0].z, f3 = v[0].w;
      float f4 = v[1].x, f5 = v[1].y, f6 = v[1].z, f7 = v[1].w;
      float sq = 0.f;
      sq = fmaf(f0, f0, sq); sq = fmaf(f1, f1, sq);
      sq = fmaf(f2, f2, sq); sq = fmaf(f3, f3, sq);
      sq = fmaf(f4, f4, sq); sq = fmaf(f5, f5, sq);
      sq = fmaf(f6, f6, sq); sq = fmaf(f7, f7, sq);
      *(uint4*)&sXh[r][q * 8] =
          uint4{pk16(f0, f1), pk16(f2, f3), pk16(f4, f5), pk16(f6, f7)};
      // threads 8r..8r+7 (same wave) share row r
      sq += __shfl_xor(sq, 1);
      sq += __shfl_xor(sq, 2);
      sq += __shfl_xor(sq, 4);
      if (q == 0) sX2[r] = -0.5f * LOG2E * sq;
    }
    __syncthreads();  // strip ready

    // prefetch next strip (issued after the barrier: retires under compute,
    // next top-of-loop barrier drains it already-complete — R5 lesson)
    if (it < NITER - 1) {
      const float* p =
          x + ((size_t)(blockIdx.x + (it + 1) * GRIDN) * 32 + r) * 64 + q * 8;
      v[0] = *(const float4*)(p);
      v[1] = *(const float4*)(p + 4);
    }

    // ---- per 16-row sub-tile: scores -> exp2 -> P -> transpose -> hist ----
#pragma unroll
    for (int t2 = 0; t2 < 2; ++t2) {
      half8v xh0 = *(const half8v*)&sXh[t2 * 16 + l15][quad * 8];
      half8v xh1 = *(const half8v*)&sXh[t2 * 16 + l15][32 + quad * 8];
      float4 m2x = *(const float4*)&sX2[t2 * 16 + quad * 4];

      // stage A: 2 MFMAs per o-tile (fp16 x * fp16 c, both RNE)
      half4v P[2];
#pragma unroll
      for (int oo = 0; oo < 2; ++oo) {
        floatx4 acc = {m2x.x + m2c[oo], m2x.y + m2c[oo],
                       m2x.z + m2c[oo], m2x.w + m2c[oo]};
        acc = mfma32(xh0, chi[oo][0], acc);
        acc = mfma32(xh1, chi[oo][1], acc);
        // acc == log2e*(-d/2) + 38 ; C-frag == K=16 A-frag (R8-verified)
        P[oo] = mkh4(pk16(EXP2F(acc[0]), EXP2F(acc[1])),
                     pk16(EXP2F(acc[2]), EXP2F(acc[3])));
      }

      // transpose x via MFMA identity (R8-verified): b64 row-major reads
      half4v XT[4];
#pragma unroll
      for (int itl = 0; itl < 4; ++itl) {
        half4v ax = *(const half4v*)&sXh[t2 * 16 + l15][itl * 16 + quad * 4];
        floatx4 z = {0.f, 0.f, 0.f, 0.f};
        floatx4 d = mfma16(ax, iden, z);
        XT[itl] = mkh4(pk16z(d[0], d[1]), pk16z(d[2], d[3]));  // exact
      }

      // stage B: hist += P * X^T (K=16)
#pragma unroll
      for (int oo = 0; oo < 2; ++oo)
#pragma unroll
        for (int itl = 0; itl < 4; ++itl)
          hacc[oo][itl] = mfma16(P[oo], XT[itl], hacc[oo][itl]);
    }
  }

  // ---- epilogue (unscale by 2^-38, exact) ----
  // D: i = itl*16 + l15, o = (2w+oo)*16 + quad*4 + e
  if (use_ws) {
    float* part = ws + (size_t)blockIdx.x * 8192;
#pragma unroll
    for (int oo = 0; oo < 2; ++oo)
#pragma unroll
      for (int itl = 0; itl < 4; ++itl)
#pragma unroll
        for (int e = 0; e < 4; ++e) {
          int o = (2 * w + oo) * 16 + quad * 4 + e;
          int i = itl * 16 + l15;
          part[o * 64 + i] = hacc[oo][itl][e] * PUNSCALE;
        }
  } else {
#pragma unroll
    for (int oo = 0; oo < 2; ++oo)
#pragma unroll
      for (int itl = 0; itl < 4; ++itl)
#pragma unroll
        for (int e = 0; e < 4; ++e) {
          int o = (2 * w + oo) * 16 + quad * 4 + e;
          int i = itl * 16 + l15;
          atomicAdd(out + o * 64 + i, hacc[oo][itl][e] * PUNSCALE);
        }
  }
}

// sum 2048 per-block partials -> out. 65536 threads: 8 parts x 8192 elems,
// each thread sums 256 partials (coalesced over e), one atomic per thread.
__global__ void reduce_kernel(const float* __restrict__ ws, float* __restrict__ out) {
  const int tid = blockIdx.x * 256 + threadIdx.x;  // 0..65535
  const int e = tid & 8191;
  const int part = tid >> 13;                      // 0..7
  const float* p = ws + (size_t)part * 256 * 8192 + e;
  float s = 0.f;
#pragma unroll 8
  for (int b = 0; b < 256; ++b) s += p[(size_t)b * 8192];
  atomicAdd(out + e, s);
}

__global__ void zero_out_kernel(float* out, int n) {
  int i = blockIdx.x * 256 + threadIdx.x;
  if (i < n) out[i] = 0.f;
}

extern "C" void kernel_launch(void* const* d_in, const int* in_sizes, int n_in,
                              void* d_out, int out_size, void* d_ws, size_t ws_size,
                              hipStream_t stream) {
  (void)in_sizes; (void)n_in;
  const float* x = (const float*)d_in[0];        // [524288, 64]
  const float* c = (const float*)d_in[1];        // [128, 64]
  float* out = (float*)d_out;                    // [128, 64]
  float* ws  = (float*)d_ws;

  const int use_ws = (ws_size >= (size_t)GRIDN * 8192 * sizeof(float)) ? 1 : 0;

  zero_out_kernel<<<(out_size + 255) / 256, 256, 0, stream>>>(out, out_size);
  rbf_hist_kernel<<<GRIDN, 256, 0, stream>>>(x, c, out, ws, use_ws);
  if (use_ws)
    reduce_kernel<<<256, 256, 0, stream>>>(ws, out);
}

// Round 11
// 208.997 us; speedup vs baseline: 1.1873x; 1.0392x over previous
//
#include <hip/hip_runtime.h>
#include <stdint.h>

// ---------------------------------------------------------------------------
// Fused RBF histogram:  hist[o,i] = sum_n exp(-||x_n - c_o||^2 / 2) * x[n,i]
// N=524288, IN=64, OUT=128.  fp32 in/out.
//
// R11: traffic + VALU trims + 2-deep prefetch on the R10 structure.
// Evidence: kernel pinned ~60-68us across occupancy 2->32 waves/CU,
// barriers 0->3, LDS 5->37KB. Bottom-up pipe sums: VALU ~25us (matches
// measured VALUBusy 32% x 80us in R1/R9), LDS ~10, HBM ~15, MFMA ~4 —
// phases serialize, pipes approximately add. This round:
//  - grid 1024 (was 2048): halves partial-write (67->33MB) + reduce read.
//  - 2-deep prefetch, parity-unrolled (vA/vB; no reg-copy => no forced
//    vmcnt drain): loads get 2 compute phases to land instead of 1.
//  - P packed with 1-inst RTZ cvt_pkrtz (was RNE 4-inst): P rel err
//    5e-4 -> 1e-3, absmax ~2-4e-11 vs 1.11e-10 threshold (margin kept).
//  - R8/R10 verified core: P-in-regs identity, transpose-MFMA, +38 bias.
// ---------------------------------------------------------------------------

typedef _Float16 half8v __attribute__((ext_vector_type(8)));
typedef _Float16 half4v __attribute__((ext_vector_type(4)));
typedef __fp16  fp16x2 __attribute__((ext_vector_type(2)));
typedef float floatx4 __attribute__((ext_vector_type(4)));

#define GRIDN 1024       // 4 blocks/CU x 256 CUs
#define NITER 16         // 16384 32-row strips / 1024 blocks
#define LOG2E 1.4426950408889634f
#define PBIAS 38.0f                       // P scaled by 2^38 into fp16 range
#define PUNSCALE 3.637978807091713e-12f   // 2^-38 (exact power of two)

#if __has_builtin(__builtin_amdgcn_exp2f)
#define EXP2F(x) __builtin_amdgcn_exp2f(x)
#else
#define EXP2F(x) exp2f(x)
#endif

// pack two fp32 -> fp16x2, RTZ (1 inst v_cvt_pkrtz_f16_f32)
static __device__ __forceinline__ unsigned int pk16z(float a, float b) {
  fp16x2 h = __builtin_amdgcn_cvt_pkrtz(a, b);
  return __builtin_bit_cast(unsigned int, h);
}
// pack two fp32 -> fp16x2, RNE — for x and c (their error dominates)
static __device__ __forceinline__ unsigned int pk16(float a, float b) {
  unsigned short ha = __builtin_bit_cast(unsigned short, (_Float16)a);
  unsigned short hb = __builtin_bit_cast(unsigned short, (_Float16)b);
  return (unsigned int)ha | ((unsigned int)hb << 16);
}
static __device__ __forceinline__ half4v mkh4(unsigned int lo, unsigned int hi) {
  uint2 u{lo, hi};
  return __builtin_bit_cast(half4v, u);
}
static __device__ __forceinline__ half8v mkh8(unsigned int a, unsigned int b,
                                              unsigned int c, unsigned int d) {
  uint4 u{a, b, c, d};
  return __builtin_bit_cast(half8v, u);
}

static __device__ __forceinline__ floatx4 mfma32(half8v a, half8v b, floatx4 c) {
  return __builtin_amdgcn_mfma_f32_16x16x32_f16(a, b, c, 0, 0, 0);
}
static __device__ __forceinline__ floatx4 mfma16(half4v a, half4v b, floatx4 c) {
  return __builtin_amdgcn_mfma_f32_16x16x16f16(a, b, c, 0, 0, 0);
}

// sXh row stride 72 shorts = 144 B: 16B-aligned rows, bank step 4 words
// -> <=2-way conflicts on b128/b64 frag reads (free per m136).
#define LSTR 72

__global__ __launch_bounds__(256, 4) void rbf_hist_kernel(
    const float* __restrict__ x, const float* __restrict__ c,
    float* __restrict__ out, float* __restrict__ ws, int use_ws) {
  __shared__ unsigned short sXh[32][LSTR];  // fp16(x) strip, row-major [n][i]
  __shared__ float          sX2[32];        // -0.5*log2e*||x_n||^2 (fp32 exact)

  const int t    = threadIdx.x;    // 0..255
  const int lane = t & 63;
  const int w    = t >> 6;         // wave 0..3; owns o-tiles {2w, 2w+1}
  const int l15  = lane & 15;
  const int quad = lane >> 4;

  // ---- one-time: c*log2e fp16 (RNE) fragments for this wave's 2 o-tiles ----
  half8v chi[2][2];
  float m2c[2];                    // -0.5*log2e*||c_o||^2 + PBIAS
#pragma unroll
  for (int oo = 0; oo < 2; ++oo) {
    const int ot = 2 * w + oo;
    float sq = 0.f;
#pragma unroll
    for (int s = 0; s < 2; ++s) {
      const float* p = c + (ot * 16 + l15) * 64 + s * 32 + quad * 8;
      float4 va = *(const float4*)(p);
      float4 vb = *(const float4*)(p + 4);
      float f[8] = {va.x, va.y, va.z, va.w, vb.x, vb.y, vb.z, vb.w};
      unsigned int h[4];
#pragma unroll
      for (int jp = 0; jp < 4; ++jp) {
        float a = f[2 * jp], b = f[2 * jp + 1];
        sq = fmaf(a, a, sq);
        sq = fmaf(b, b, sq);
        h[jp] = pk16(a * LOG2E, b * LOG2E);   // RNE
      }
      chi[oo][s] = mkh8(h[0], h[1], h[2], h[3]);
    }
    sq += __shfl_xor(sq, 16);
    sq += __shfl_xor(sq, 32);
    m2c[oo] = fmaf(-0.5f * LOG2E, sq, PBIAS);
  }

  // identity B-frag for the transpose MFMA: I[k=quad*4+j][col=l15]
  half4v iden;
  {
    float e0 = (quad * 4 + 0 == l15) ? 1.f : 0.f;
    float e1 = (quad * 4 + 1 == l15) ? 1.f : 0.f;
    float e2 = (quad * 4 + 2 == l15) ? 1.f : 0.f;
    float e3 = (quad * 4 + 3 == l15) ? 1.f : 0.f;
    iden = mkh4(pk16z(e0, e1), pk16z(e2, e3));  // exact
  }

  // persistent histogram accumulators: 2 o-tiles x 4 i-tiles (scaled 2^38)
  floatx4 hacc[2][4];
#pragma unroll
  for (int a = 0; a < 2; ++a)
#pragma unroll
    for (int b = 0; b < 4; ++b) {
      floatx4 z = {0.f, 0.f, 0.f, 0.f};
      hacc[a][b] = z;
    }

  // staging map: thread t -> row r=t>>3 (0..31), cols q*8 .. q*8+7 (q=t&7)
  const int r = t >> 3, q = t & 7;

  // 2-deep prefetch ring: vA holds even strips, vB odd strips.
  float4 vA[2], vB[2];
  {
    const float* pA = x + ((size_t)blockIdx.x * 32 + r) * 64 + q * 8;
    vA[0] = *(const float4*)(pA);
    vA[1] = *(const float4*)(pA + 4);
    const float* pB =
        x + ((size_t)(blockIdx.x + GRIDN) * 32 + r) * 64 + q * 8;
    vB[0] = *(const float4*)(pB);
    vB[1] = *(const float4*)(pB + 4);
  }

#pragma unroll 1
  for (int it = 0; it < NITER; it += 2) {
#pragma unroll
    for (int par = 0; par < 2; ++par) {
      float4* v = (par == 0) ? vA : vB;

      __syncthreads();  // prev strip's sXh reads done -> safe to overwrite

      // ---- staging: fp16 RNE convert -> LDS row-major + exact fp32 x2 ----
      {
        float f0 = v[0].x, f1 = v[0].y, f2 = v[0].z, f3 = v[0].w;
        float f4 = v[1].x, f5 = v[1].y, f6 = v[1].z, f7 = v[1].w;
        float sq = 0.f;
        sq = fmaf(f0, f0, sq); sq = fmaf(f1, f1, sq);
        sq = fmaf(f2, f2, sq); sq = fmaf(f3, f3, sq);
        sq = fmaf(f4, f4, sq); sq = fmaf(f5, f5, sq);
        sq = fmaf(f6, f6, sq); sq = fmaf(f7, f7, sq);
        *(uint4*)&sXh[r][q * 8] =
            uint4{pk16(f0, f1), pk16(f2, f3), pk16(f4, f5), pk16(f6, f7)};
        // threads 8r..8r+7 (same wave) share row r
        sq += __shfl_xor(sq, 1);
        sq += __shfl_xor(sq, 2);
        sq += __shfl_xor(sq, 4);
        if (q == 0) sX2[r] = -0.5f * LOG2E * sq;
      }
      __syncthreads();  // strip ready

      // prefetch strip it+par+2 into this parity's buffer (issued after the
      // barrier — R5 lesson; lands during ~2 compute phases, drained
      // already-complete at the staging that consumes it)
      if (it + par + 2 < NITER) {
        const float* p = x +
            ((size_t)(blockIdx.x + (it + par + 2) * GRIDN) * 32 + r) * 64 +
            q * 8;
        v[0] = *(const float4*)(p);
        v[1] = *(const float4*)(p + 4);
      }

      // ---- per 16-row sub-tile: scores -> exp2 -> P -> transpose -> hist ----
#pragma unroll
      for (int t2 = 0; t2 < 2; ++t2) {
        half8v xh0 = *(const half8v*)&sXh[t2 * 16 + l15][quad * 8];
        half8v xh1 = *(const half8v*)&sXh[t2 * 16 + l15][32 + quad * 8];
        float4 m2x = *(const float4*)&sX2[t2 * 16 + quad * 4];

        // stage A: 2 MFMAs per o-tile (fp16 x * fp16 c, both RNE)
        half4v P[2];
#pragma unroll
        for (int oo = 0; oo < 2; ++oo) {
          floatx4 acc = {m2x.x + m2c[oo], m2x.y + m2c[oo],
                         m2x.z + m2c[oo], m2x.w + m2c[oo]};
          acc = mfma32(xh0, chi[oo][0], acc);
          acc = mfma32(xh1, chi[oo][1], acc);
          // acc == log2e*(-d/2) + 38 ; C-frag == K=16 A-frag (R8-verified)
          P[oo] = mkh4(pk16z(EXP2F(acc[0]), EXP2F(acc[1])),
                       pk16z(EXP2F(acc[2]), EXP2F(acc[3])));  // RTZ, 1 inst
        }

        // transpose x via MFMA identity (R8-verified): b64 row-major reads
        half4v XT[4];
#pragma unroll
        for (int itl = 0; itl < 4; ++itl) {
          half4v ax = *(const half4v*)&sXh[t2 * 16 + l15][itl * 16 + quad * 4];
          floatx4 z = {0.f, 0.f, 0.f, 0.f};
          floatx4 d = mfma16(ax, iden, z);
          XT[itl] = mkh4(pk16z(d[0], d[1]), pk16z(d[2], d[3]));  // exact
        }

        // stage B: hist += P * X^T (K=16)
#pragma unroll
        for (int oo = 0; oo < 2; ++oo)
#pragma unroll
          for (int itl = 0; itl < 4; ++itl)
            hacc[oo][itl] = mfma16(P[oo], XT[itl], hacc[oo][itl]);
      }
    }
  }

  // ---- epilogue (unscale by 2^-38, exact) ----
  // D: i = itl*16 + l15, o = (2w+oo)*16 + quad*4 + e
  if (use_ws) {
    float* part = ws + (size_t)blockIdx.x * 8192;
#pragma unroll
    for (int oo = 0; oo < 2; ++oo)
#pragma unroll
      for (int itl = 0; itl < 4; ++itl)
#pragma unroll
        for (int e = 0; e < 4; ++e) {
          int o = (2 * w + oo) * 16 + quad * 4 + e;
          int i = itl * 16 + l15;
          part[o * 64 + i] = hacc[oo][itl][e] * PUNSCALE;
        }
  } else {
#pragma unroll
    for (int oo = 0; oo < 2; ++oo)
#pragma unroll
      for (int itl = 0; itl < 4; ++itl)
#pragma unroll
        for (int e = 0; e < 4; ++e) {
          int o = (2 * w + oo) * 16 + quad * 4 + e;
          int i = itl * 16 + l15;
          atomicAdd(out + o * 64 + i, hacc[oo][itl][e] * PUNSCALE);
        }
  }
}

// sum 1024 per-block partials -> out. 32768 threads: 4 parts x 8192 elems,
// each thread sums 256 partials (coalesced over e), one atomic per thread.
__global__ void reduce_kernel(const float* __restrict__ ws, float* __restrict__ out) {
  const int tid = blockIdx.x * 256 + threadIdx.x;  // 0..32767
  const int e = tid & 8191;
  const int part = tid >> 13;                      // 0..3
  const float* p = ws + (size_t)part * 256 * 8192 + e;
  float s = 0.f;
#pragma unroll 8
  for (int b = 0; b < 256; ++b) s += p[(size_t)b * 8192];
  atomicAdd(out + e, s);
}

__global__ void zero_out_kernel(float* out, int n) {
  int i = blockIdx.x * 256 + threadIdx.x;
  if (i < n) out[i] = 0.f;
}

extern "C" void kernel_launch(void* const* d_in, const int* in_sizes, int n_in,
                              void* d_out, int out_size, void* d_ws, size_t ws_size,
                              hipStream_t stream) {
  (void)in_sizes; (void)n_in;
  const float* x = (const float*)d_in[0];        // [524288, 64]
  const float* c = (const float*)d_in[1];        // [128, 64]
  float* out = (float*)d_out;                    // [128, 64]
  float* ws  = (float*)d_ws;

  const int use_ws = (ws_size >= (size_t)GRIDN * 8192 * sizeof(float)) ? 1 : 0;

  zero_out_kernel<<<(out_size + 255) / 256, 256, 0, stream>>>(out, out_size);
  rbf_hist_kernel<<<GRIDN, 256, 0, stream>>>(x, c, out, ws, use_ws);
  if (use_ws)
    reduce_kernel<<<128, 256, 0, stream>>>(ws, out);
}

// Round 12
// 199.690 us; speedup vs baseline: 1.2427x; 1.0466x over previous
//
#include <hip/hip_runtime.h>
#include <stdint.h>

// ---------------------------------------------------------------------------
// Fused RBF histogram:  hist[o,i] = sum_n exp(-||x_n - c_o||^2 / 2) * x[n,i]
// N=524288, IN=64, OUT=128.  fp32 in/out.
//
// R12: traffic + amortization. Kernel pinned ~55-60us across 7 structural
// axes (occupancy 2->32 w/CU, barriers 0->3, LDS 5->37KB, prefetch 0->2);
// remaining levers are total bytes and prologue amortization:
//  - grid 512 (2 blocks/CU, 8 waves/CU — same residency as best R8),
//    NITER 32: ws partial traffic halves (33->16.8MB), prologue amortizes
//    2-4x better.
//  - reduce: 4 parts x 128 coalesced sums (128 blocks), ~16.8MB read.
//  - core unchanged (R8/R11-verified): fp16 MFMA32 scores with c*log2e RNE,
//    P-in-registers C/D==A-frag identity, transpose-MFMA, exp2 +38 bias,
//    RTZ P-pack (absmax 2.9e-11 measured, 3.8x margin).
// ---------------------------------------------------------------------------

typedef _Float16 half8v __attribute__((ext_vector_type(8)));
typedef _Float16 half4v __attribute__((ext_vector_type(4)));
typedef __fp16  fp16x2 __attribute__((ext_vector_type(2)));
typedef float floatx4 __attribute__((ext_vector_type(4)));

#define GRIDN 512        // 2 blocks/CU x 256 CUs
#define NITER 32         // 16384 32-row strips / 512 blocks
#define LOG2E 1.4426950408889634f
#define PBIAS 38.0f                       // P scaled by 2^38 into fp16 range
#define PUNSCALE 3.637978807091713e-12f   // 2^-38 (exact power of two)

#if __has_builtin(__builtin_amdgcn_exp2f)
#define EXP2F(x) __builtin_amdgcn_exp2f(x)
#else
#define EXP2F(x) exp2f(x)
#endif

// pack two fp32 -> fp16x2, RTZ (1 inst v_cvt_pkrtz_f16_f32)
static __device__ __forceinline__ unsigned int pk16z(float a, float b) {
  fp16x2 h = __builtin_amdgcn_cvt_pkrtz(a, b);
  return __builtin_bit_cast(unsigned int, h);
}
// pack two fp32 -> fp16x2, RNE — for x and c (their quantization dominates)
static __device__ __forceinline__ unsigned int pk16(float a, float b) {
  unsigned short ha = __builtin_bit_cast(unsigned short, (_Float16)a);
  unsigned short hb = __builtin_bit_cast(unsigned short, (_Float16)b);
  return (unsigned int)ha | ((unsigned int)hb << 16);
}
static __device__ __forceinline__ half4v mkh4(unsigned int lo, unsigned int hi) {
  uint2 u{lo, hi};
  return __builtin_bit_cast(half4v, u);
}
static __device__ __forceinline__ half8v mkh8(unsigned int a, unsigned int b,
                                              unsigned int c, unsigned int d) {
  uint4 u{a, b, c, d};
  return __builtin_bit_cast(half8v, u);
}

static __device__ __forceinline__ floatx4 mfma32(half8v a, half8v b, floatx4 c) {
  return __builtin_amdgcn_mfma_f32_16x16x32_f16(a, b, c, 0, 0, 0);
}
static __device__ __forceinline__ floatx4 mfma16(half4v a, half4v b, floatx4 c) {
  return __builtin_amdgcn_mfma_f32_16x16x16f16(a, b, c, 0, 0, 0);
}

// sXh row stride 72 shorts = 144 B: 16B-aligned rows, bank step 4 words
// -> <=2-way conflicts on b128/b64 frag reads (free per m136).
#define LSTR 72

__global__ __launch_bounds__(256, 4) void rbf_hist_kernel(
    const float* __restrict__ x, const float* __restrict__ c,
    float* __restrict__ out, float* __restrict__ ws, int use_ws) {
  __shared__ unsigned short sXh[32][LSTR];  // fp16(x) strip, row-major [n][i]
  __shared__ float          sX2[32];        // -0.5*log2e*||x_n||^2 (fp32 exact)

  const int t    = threadIdx.x;    // 0..255
  const int lane = t & 63;
  const int w    = t >> 6;         // wave 0..3; owns o-tiles {2w, 2w+1}
  const int l15  = lane & 15;
  const int quad = lane >> 4;

  // ---- one-time: c*log2e fp16 (RNE) fragments for this wave's 2 o-tiles ----
  half8v chi[2][2];
  float m2c[2];                    // -0.5*log2e*||c_o||^2 + PBIAS
#pragma unroll
  for (int oo = 0; oo < 2; ++oo) {
    const int ot = 2 * w + oo;
    float sq = 0.f;
#pragma unroll
    for (int s = 0; s < 2; ++s) {
      const float* p = c + (ot * 16 + l15) * 64 + s * 32 + quad * 8;
      float4 va = *(const float4*)(p);
      float4 vb = *(const float4*)(p + 4);
      float f[8] = {va.x, va.y, va.z, va.w, vb.x, vb.y, vb.z, vb.w};
      unsigned int h[4];
#pragma unroll
      for (int jp = 0; jp < 4; ++jp) {
        float a = f[2 * jp], b = f[2 * jp + 1];
        sq = fmaf(a, a, sq);
        sq = fmaf(b, b, sq);
        h[jp] = pk16(a * LOG2E, b * LOG2E);   // RNE
      }
      chi[oo][s] = mkh8(h[0], h[1], h[2], h[3]);
    }
    sq += __shfl_xor(sq, 16);
    sq += __shfl_xor(sq, 32);
    m2c[oo] = fmaf(-0.5f * LOG2E, sq, PBIAS);
  }

  // identity B-frag for the transpose MFMA: I[k=quad*4+j][col=l15]
  half4v iden;
  {
    float e0 = (quad * 4 + 0 == l15) ? 1.f : 0.f;
    float e1 = (quad * 4 + 1 == l15) ? 1.f : 0.f;
    float e2 = (quad * 4 + 2 == l15) ? 1.f : 0.f;
    float e3 = (quad * 4 + 3 == l15) ? 1.f : 0.f;
    iden = mkh4(pk16z(e0, e1), pk16z(e2, e3));  // exact
  }

  // persistent histogram accumulators: 2 o-tiles x 4 i-tiles (scaled 2^38)
  floatx4 hacc[2][4];
#pragma unroll
  for (int a = 0; a < 2; ++a)
#pragma unroll
    for (int b = 0; b < 4; ++b) {
      floatx4 z = {0.f, 0.f, 0.f, 0.f};
      hacc[a][b] = z;
    }

  // staging map: thread t -> row r=t>>3 (0..31), cols q*8 .. q*8+7 (q=t&7)
  const int r = t >> 3, q = t & 7;

  // 2-deep prefetch ring: vA holds even strips, vB odd strips.
  float4 vA[2], vB[2];
  {
    const float* pA = x + ((size_t)blockIdx.x * 32 + r) * 64 + q * 8;
    vA[0] = *(const float4*)(pA);
    vA[1] = *(const float4*)(pA + 4);
    const float* pB =
        x + ((size_t)(blockIdx.x + GRIDN) * 32 + r) * 64 + q * 8;
    vB[0] = *(const float4*)(pB);
    vB[1] = *(const float4*)(pB + 4);
  }

#pragma unroll 1
  for (int it = 0; it < NITER; it += 2) {
#pragma unroll
    for (int par = 0; par < 2; ++par) {
      float4* v = (par == 0) ? vA : vB;

      __syncthreads();  // prev strip's sXh reads done -> safe to overwrite

      // ---- staging: fp16 RNE convert -> LDS row-major + exact fp32 x2 ----
      {
        float f0 = v[0].x, f1 = v[0].y, f2 = v[0].z, f3 = v[0].w;
        float f4 = v[1].x, f5 = v[1].y, f6 = v[1].z, f7 = v[1].w;
        float sq = 0.f;
        sq = fmaf(f0, f0, sq); sq = fmaf(f1, f1, sq);
        sq = fmaf(f2, f2, sq); sq = fmaf(f3, f3, sq);
        sq = fmaf(f4, f4, sq); sq = fmaf(f5, f5, sq);
        sq = fmaf(f6, f6, sq); sq = fmaf(f7, f7, sq);
        *(uint4*)&sXh[r][q * 8] =
            uint4{pk16(f0, f1), pk16(f2, f3), pk16(f4, f5), pk16(f6, f7)};
        // threads 8r..8r+7 (same wave) share row r
        sq += __shfl_xor(sq, 1);
        sq += __shfl_xor(sq, 2);
        sq += __shfl_xor(sq, 4);
        if (q == 0) sX2[r] = -0.5f * LOG2E * sq;
      }
      __syncthreads();  // strip ready

      // prefetch strip it+par+2 into this parity's buffer (issued after the
      // barrier — R5 lesson; lands during ~2 compute phases)
      if (it + par + 2 < NITER) {
        const float* p = x +
            ((size_t)(blockIdx.x + (it + par + 2) * GRIDN) * 32 + r) * 64 +
            q * 8;
        v[0] = *(const float4*)(p);
        v[1] = *(const float4*)(p + 4);
      }

      // ---- per 16-row sub-tile: scores -> exp2 -> P -> transpose -> hist ----
#pragma unroll
      for (int t2 = 0; t2 < 2; ++t2) {
        half8v xh0 = *(const half8v*)&sXh[t2 * 16 + l15][quad * 8];
        half8v xh1 = *(const half8v*)&sXh[t2 * 16 + l15][32 + quad * 8];
        float4 m2x = *(const float4*)&sX2[t2 * 16 + quad * 4];

        // stage A: 2 MFMAs per o-tile (fp16 x * fp16 c, both RNE)
        half4v P[2];
#pragma unroll
        for (int oo = 0; oo < 2; ++oo) {
          floatx4 acc = {m2x.x + m2c[oo], m2x.y + m2c[oo],
                         m2x.z + m2c[oo], m2x.w + m2c[oo]};
          acc = mfma32(xh0, chi[oo][0], acc);
          acc = mfma32(xh1, chi[oo][1], acc);
          // acc == log2e*(-d/2) + 38 ; C-frag == K=16 A-frag (R8-verified)
          P[oo] = mkh4(pk16z(EXP2F(acc[0]), EXP2F(acc[1])),
                       pk16z(EXP2F(acc[2]), EXP2F(acc[3])));  // RTZ, 1 inst
        }

        // transpose x via MFMA identity (R8-verified): b64 row-major reads
        half4v XT[4];
#pragma unroll
        for (int itl = 0; itl < 4; ++itl) {
          half4v ax = *(const half4v*)&sXh[t2 * 16 + l15][itl * 16 + quad * 4];
          floatx4 z = {0.f, 0.f, 0.f, 0.f};
          floatx4 d = mfma16(ax, iden, z);
          XT[itl] = mkh4(pk16z(d[0], d[1]), pk16z(d[2], d[3]));  // exact
        }

        // stage B: hist += P * X^T (K=16)
#pragma unroll
        for (int oo = 0; oo < 2; ++oo)
#pragma unroll
          for (int itl = 0; itl < 4; ++itl)
            hacc[oo][itl] = mfma16(P[oo], XT[itl], hacc[oo][itl]);
      }
    }
  }

  // ---- epilogue (unscale by 2^-38, exact) ----
  // D: i = itl*16 + l15, o = (2w+oo)*16 + quad*4 + e
  if (use_ws) {
    float* part = ws + (size_t)blockIdx.x * 8192;
#pragma unroll
    for (int oo = 0; oo < 2; ++oo)
#pragma unroll
      for (int itl = 0; itl < 4; ++itl)
#pragma unroll
        for (int e = 0; e < 4; ++e) {
          int o = (2 * w + oo) * 16 + quad * 4 + e;
          int i = itl * 16 + l15;
          part[o * 64 + i] = hacc[oo][itl][e] * PUNSCALE;
        }
  } else {
#pragma unroll
    for (int oo = 0; oo < 2; ++oo)
#pragma unroll
      for (int itl = 0; itl < 4; ++itl)
#pragma unroll
        for (int e = 0; e < 4; ++e) {
          int o = (2 * w + oo) * 16 + quad * 4 + e;
          int i = itl * 16 + l15;
          atomicAdd(out + o * 64 + i, hacc[oo][itl][e] * PUNSCALE);
        }
  }
}

// sum 512 per-block partials -> out. 32768 threads: 4 parts x 8192 elems,
// each thread sums 128 partials (coalesced over e), one atomic per thread.
__global__ void reduce_kernel(const float* __restrict__ ws, float* __restrict__ out) {
  const int tid = blockIdx.x * 256 + threadIdx.x;  // 0..32767
  const int e = tid & 8191;
  const int part = tid >> 13;                      // 0..3
  const float* p = ws + (size_t)part * 128 * 8192 + e;
  float s = 0.f;
#pragma unroll 8
  for (int b = 0; b < 128; ++b) s += p[(size_t)b * 8192];
  atomicAdd(out + e, s);
}

__global__ void zero_out_kernel(float* out, int n) {
  int i = blockIdx.x * 256 + threadIdx.x;
  if (i < n) out[i] = 0.f;
}

extern "C" void kernel_launch(void* const* d_in, const int* in_sizes, int n_in,
                              void* d_out, int out_size, void* d_ws, size_t ws_size,
                              hipStream_t stream) {
  (void)in_sizes; (void)n_in;
  const float* x = (const float*)d_in[0];        // [524288, 64]
  const float* c = (const float*)d_in[1];        // [128, 64]
  float* out = (float*)d_out;                    // [128, 64]
  float* ws  = (float*)d_ws;

  const int use_ws = (ws_size >= (size_t)GRIDN * 8192 * sizeof(float)) ? 1 : 0;

  zero_out_kernel<<<(out_size + 255) / 256, 256, 0, stream>>>(out, out_size);
  rbf_hist_kernel<<<GRIDN, 256, 0, stream>>>(x, c, out, ws, use_ws);
  if (use_ws)
    reduce_kernel<<<128, 256, 0, stream>>>(ws, out);
}